// Round 1
// baseline (257.767 us; speedup 1.0000x reference)
//
#include <hip/hip_runtime.h>

#define BB   16
#define FIN  16
#define FOUT 16
#define HH   384
#define WW   384
#define LAT  512
#define NMIX 8
#define HW   (HH * WW)          // 147456
#define HW4  (HW / 4)           // 36864 float4 per channel plane
#define WSTRIDE 272             // per-sample ws floats: 256 kernel + 16 bias

typedef float f32x4 __attribute__((ext_vector_type(4)));

// ---------------------------------------------------------------------------
// Kernel A (tiny, 16 blocks): fold per-sample dynamic weights ONCE per sample.
//   mix[m]   = lat[b] . w_dyn[m] + b_dyn[m]
//   k[o][i]  = sum_m mix[m] * kernel_mix[m][o][i]   -> ws[b*272 + o*16+i]
//   bias[o]  = sum_m mix[m] * bias_mix[m][o]        -> ws[b*272 + 256+o]
// Removes the block-redundant mix computation (was done 2304x, now 16x).
// ---------------------------------------------------------------------------
__global__ __launch_bounds__(256)
void mixconv_weights(const float* __restrict__ lat,
                     const float* __restrict__ kernel_mix,   // [NMIX][FOUT][FIN]
                     const float* __restrict__ bias_mix,     // [NMIX][FOUT]
                     const float* __restrict__ w_dyn,        // [NMIX][LAT]
                     const float* __restrict__ b_dyn,        // [NMIX]
                     float* __restrict__ ws) {
    __shared__ float part[NMIX][32];
    __shared__ float mix_s[NMIX];
    const int t = threadIdx.x;
    const int b = blockIdx.x;

    {
        const int m = t & (NMIX - 1);       // 0..7
        const int c = t >> 3;               // 0..31, chunk of 16 elements
        const f32x4* lv = (const f32x4*)(lat + (size_t)b * LAT + c * 16);
        const f32x4* wv = (const f32x4*)(w_dyn + (size_t)m * LAT + c * 16);
        float acc = 0.f;
#pragma unroll
        for (int j = 0; j < 4; ++j) {
            f32x4 a = lv[j], w = wv[j];
            acc += a.x * w.x + a.y * w.y + a.z * w.z + a.w * w.w;
        }
        part[m][c] = acc;
    }
    __syncthreads();
    if (t < NMIX) {
        float s = 0.f;
#pragma unroll
        for (int c = 0; c < 32; ++c) s += part[t][c];
        mix_s[t] = s + b_dyn[t];
    }
    __syncthreads();

    // thread t -> (o = t>>4, i = t&15); global reads coalesced
    float kacc = 0.f;
#pragma unroll
    for (int m = 0; m < NMIX; ++m)
        kacc += mix_s[m] * kernel_mix[m * FOUT * FIN + t];
    ws[b * WSTRIDE + t] = kacc;
    if (t < FOUT) {
        float bacc = 0.f;
#pragma unroll
        for (int m = 0; m < NMIX; ++m)
            bacc += mix_s[m] * bias_mix[m * FOUT + t];
        ws[b * WSTRIDE + 256 + t] = bacc;
    }
}

// ---------------------------------------------------------------------------
// Kernel B (streaming, BARRIER-FREE):
//   - each WAVE copies the 1 KB folded weight block into its own LDS region
//     (wave-private LDS: no s_barrier needed, only lgkmcnt ordering — so the
//     16 streaming x loads are never drained by a vmcnt(0)-at-barrier)
//   - weight load is issued BEFORE the x loads, so its s_waitcnt is
//     vmcnt(16), not vmcnt(0): no serialization against the HBM streams
//   - phase 3 unchanged: 16x16 matvec, uniform-address LDS broadcast reads,
//     nontemporal f32x4 stores
// ---------------------------------------------------------------------------
__global__ __launch_bounds__(256)
void mixconv_main(const float* __restrict__ x,
                  const float* __restrict__ wk,    // ws from kernel A
                  float* __restrict__ out) {
    __shared__ float wsh[4][WSTRIDE];   // per-wave private copy (4.25 KB)
    const int t    = threadIdx.x;
    const int wid  = t >> 6;
    const int lane = t & 63;
    const int b    = blockIdx.y;

    // --- issue weight loads FIRST (L2-hot, 272 floats per block) ----------
    float wv[5];
#pragma unroll
    for (int j = 0; j < 5; ++j) {
        const int idx = lane + j * 64;
        if (idx < WSTRIDE) wv[j] = wk[b * WSTRIDE + idx];
    }

    // --- issue streaming x loads (stay in flight until phase 3) -----------
    const int p = blockIdx.x * 256 + t;     // float4 index in [0, HW4)
    const f32x4* xv = (const f32x4*)(x + (size_t)b * FIN * HW) + p;
    f32x4*       ov = (f32x4*)(out + (size_t)b * FOUT * HW) + p;

    f32x4 xi[FIN];
#pragma unroll
    for (int i = 0; i < FIN; ++i)
        xi[i] = __builtin_nontemporal_load(xv + (size_t)i * HW4);

    // --- wave-private LDS stash (no __syncthreads anywhere) ----------------
#pragma unroll
    for (int j = 0; j < 5; ++j) {
        const int idx = lane + j * 64;
        if (idx < WSTRIDE) wsh[wid][idx] = wv[j];
    }

    // --- 16x16 matvec, stream out ------------------------------------------
    const float* ksh = &wsh[wid][0];
    const float* bsh = &wsh[wid][256];
#pragma unroll
    for (int o = 0; o < FOUT; ++o) {
        const f32x4 k0 = *(const f32x4*)&ksh[o * 16 + 0];
        const f32x4 k1 = *(const f32x4*)&ksh[o * 16 + 4];
        const f32x4 k2 = *(const f32x4*)&ksh[o * 16 + 8];
        const f32x4 k3 = *(const f32x4*)&ksh[o * 16 + 12];
        const float bo = bsh[o];
        f32x4 acc = {bo, bo, bo, bo};
        acc += k0.x * xi[0];  acc += k0.y * xi[1];
        acc += k0.z * xi[2];  acc += k0.w * xi[3];
        acc += k1.x * xi[4];  acc += k1.y * xi[5];
        acc += k1.z * xi[6];  acc += k1.w * xi[7];
        acc += k2.x * xi[8];  acc += k2.y * xi[9];
        acc += k2.z * xi[10]; acc += k2.w * xi[11];
        acc += k3.x * xi[12]; acc += k3.y * xi[13];
        acc += k3.z * xi[14]; acc += k3.w * xi[15];
        __builtin_nontemporal_store(acc, ov + (size_t)o * HW4);
    }
}

// ---------------------------------------------------------------------------
extern "C" void kernel_launch(void* const* d_in, const int* in_sizes, int n_in,
                              void* d_out, int out_size, void* d_ws, size_t ws_size,
                              hipStream_t stream) {
    const float* x          = (const float*)d_in[0];
    const float* lat        = (const float*)d_in[1];
    const float* kernel_mix = (const float*)d_in[2];
    const float* bias_mix   = (const float*)d_in[3];
    const float* w_dyn      = (const float*)d_in[4];
    const float* b_dyn      = (const float*)d_in[5];
    float* out = (float*)d_out;
    float* ws  = (float*)d_ws;      // needs 16*272*4 = 17408 B

    mixconv_weights<<<dim3(BB), dim3(256), 0, stream>>>(
        lat, kernel_mix, bias_mix, w_dyn, b_dyn, ws);

    dim3 grid(HW4 / 256, BB);               // (144, 16) = 2304 blocks
    mixconv_main<<<grid, dim3(256), 0, stream>>>(x, ws, out);
}